// Round 1
// baseline (432.537 us; speedup 1.0000x reference)
//
#include <hip/hip_runtime.h>
#include <math.h>

// RWKV WKV forward scan.
// B=8, T=2048, H=2048, f32 in/out.
// One thread per (b, h) channel: 16384 threads = 256 waves = 1 wave/CU.
// Serial scan over T with register ping-pong prefetch (U timesteps/chunk)
// so the 2*U global loads of chunk n+1 are in flight while chunk n computes.

#define WKV_U 16  // timesteps per prefetch chunk

__global__ __launch_bounds__(64, 1)
void wkv_fwd(const float* __restrict__ k_, const float* __restrict__ v_,
             const float* __restrict__ td, const float* __restrict__ tf,
             float* __restrict__ out)
{
    constexpr int Tc = 2048, Hc = 2048;
    const int gid = blockIdx.x * 64 + threadIdx.x;   // 0 .. B*H-1
    const int h = gid & (Hc - 1);
    const int b = gid >> 11;                          // / 2048

    const float u = tf[h];
    const float w = -__expf(td[h]);                   // negative decay

    const size_t base = (size_t)b * Tc * Hc + h;
    const float* kp = k_ + base;
    const float* vp = v_ + base;
    float*       op = out + base;

    float a = 0.0f, bsum = 0.0f, e = -INFINITY;

    // One stabilized WKV step. Output first (uses prior state), then update.
    auto step = [&](float kt, float vt, float* outp) {
        float uk  = u + kt;
        float m   = fmaxf(e, uk);
        float wt  = __expf(uk - m);                   // in (0,1]
        float sc  = __expf(e - m);                    // exp(-inf)=0 at t=0
        float num = fmaf(wt, vt, a * sc);
        float den = fmaf(bsum, sc, wt);               // > 0 always
        *outp = num * __builtin_amdgcn_rcpf(den);
        float ew  = e + w;
        float m2  = fmaxf(ew, kt);
        float s1  = __expf(ew - m2);
        float s2  = __expf(kt - m2);
        a    = fmaf(s1, a, s2 * vt);
        bsum = fmaf(s1, bsum, s2);
        e    = m2;
    };

    // Named ping-pong buffers; all indexing is compile-time (full unroll),
    // so these live in registers, not scratch.
    float kA[WKV_U], vA[WKV_U], kB[WKV_U], vB[WKV_U];

    #pragma unroll
    for (int i = 0; i < WKV_U; ++i) {
        kA[i] = kp[(size_t)i * Hc];
        vA[i] = vp[(size_t)i * Hc];
    }

    for (int t0 = 0; t0 < Tc; t0 += 2 * WKV_U) {
        // prefetch chunk B = [t0+U, t0+2U)  (always in range: T % 2U == 0)
        #pragma unroll
        for (int i = 0; i < WKV_U; ++i) {
            kB[i] = kp[(size_t)(t0 + WKV_U + i) * Hc];
            vB[i] = vp[(size_t)(t0 + WKV_U + i) * Hc];
        }
        // compute chunk A at t0
        #pragma unroll
        for (int i = 0; i < WKV_U; ++i)
            step(kA[i], vA[i], op + (size_t)(t0 + i) * Hc);
        // prefetch chunk A = [t0+2U, t0+3U)
        if (t0 + 2 * WKV_U < Tc) {
            #pragma unroll
            for (int i = 0; i < WKV_U; ++i) {
                kA[i] = kp[(size_t)(t0 + 2 * WKV_U + i) * Hc];
                vA[i] = vp[(size_t)(t0 + 2 * WKV_U + i) * Hc];
            }
        }
        // compute chunk B at t0+U
        #pragma unroll
        for (int i = 0; i < WKV_U; ++i)
            step(kB[i], vB[i], op + (size_t)(t0 + WKV_U + i) * Hc);
    }
}

extern "C" void kernel_launch(void* const* d_in, const int* in_sizes, int n_in,
                              void* d_out, int out_size, void* d_ws, size_t ws_size,
                              hipStream_t stream) {
    const float* key   = (const float*)d_in[0];
    const float* value = (const float*)d_in[1];
    const float* td    = (const float*)d_in[2];
    const float* tf    = (const float*)d_in[3];
    float* out = (float*)d_out;

    // B*H = 16384 channels -> 256 blocks x 64 threads = 1 wave per CU.
    wkv_fwd<<<dim3(256), dim3(64), 0, stream>>>(key, value, td, tf, out);
}

// Round 3
// 388.639 us; speedup vs baseline: 1.1130x; 1.1130x over previous
//
#include <hip/hip_runtime.h>
#include <math.h>

// RWKV WKV forward scan — chunked two-pass parallel scan over T.
// B=8, T=2048, H=2048, f32. BH = 16384 independent channels.
//
// R1 was latency-bound (1 wave/CU, VALUBusy 13%, occupancy 2.9%).
// Split T into NC chunks: the stabilized state (a,b,e) composes as an
// affine map, so:
//   K1: per (channel, chunk) compute chunk-local P=(pa,pb,pe) from identity.
//       -> 256*NC waves (NC=32: 8 waves/SIMD) instead of 256.
//   K2: per channel, serial combine over NC chunks; overwrites P[c] with the
//       INCOMING state S_c for chunk c (in-place, thread-private slots).
//   K3: per (channel, chunk) re-read k,v slice, start from S_c, write out.

#define WKV_B 8
#define WKV_T 2048
#define WKV_H 2048
#define WKV_BH (WKV_B * WKV_H)
#define WKV_U 8  // prefetch half-chunk (register ping-pong)

__device__ __forceinline__ void wkv_update(float& a, float& bs, float& e,
                                           float w, float kt, float vt) {
    float ew = e + w;
    float m2 = fmaxf(ew, kt);
    float s1 = __expf(ew - m2);
    float s2 = __expf(kt - m2);
    a  = fmaf(s1, a, s2 * vt);
    bs = fmaf(s1, bs, s2);
    e  = m2;
}

// ---- K1: chunk-local state from identity ----
__global__ __launch_bounds__(256)
void wkv_pass1(const float* __restrict__ k_, const float* __restrict__ v_,
               const float* __restrict__ td,
               float* __restrict__ pa, float* __restrict__ pb,
               float* __restrict__ pe, int L)
{
    const int ch = blockIdx.x * 256 + threadIdx.x;   // 0..BH-1
    const int c  = blockIdx.y;
    const int h  = ch & (WKV_H - 1);
    const int b  = ch >> 11;
    const float w = -__expf(td[h]);

    const size_t base = (size_t)b * WKV_T * WKV_H + h + (size_t)c * L * WKV_H;
    const float* kp = k_ + base;
    const float* vp = v_ + base;

    float a = 0.0f, bs = 0.0f, e = -INFINITY;

    float kA[WKV_U], vA[WKV_U], kB[WKV_U], vB[WKV_U];
    #pragma unroll
    for (int i = 0; i < WKV_U; ++i) {
        kA[i] = kp[(size_t)i * WKV_H];
        vA[i] = vp[(size_t)i * WKV_H];
    }
    for (int t0 = 0; t0 < L; t0 += 2 * WKV_U) {   // L is a multiple of 16
        #pragma unroll
        for (int i = 0; i < WKV_U; ++i) {
            kB[i] = kp[(size_t)(t0 + WKV_U + i) * WKV_H];
            vB[i] = vp[(size_t)(t0 + WKV_U + i) * WKV_H];
        }
        #pragma unroll
        for (int i = 0; i < WKV_U; ++i) wkv_update(a, bs, e, w, kA[i], vA[i]);
        if (t0 + 2 * WKV_U < L) {
            #pragma unroll
            for (int i = 0; i < WKV_U; ++i) {
                kA[i] = kp[(size_t)(t0 + 2 * WKV_U + i) * WKV_H];
                vA[i] = vp[(size_t)(t0 + 2 * WKV_U + i) * WKV_H];
            }
        }
        #pragma unroll
        for (int i = 0; i < WKV_U; ++i) wkv_update(a, bs, e, w, kB[i], vB[i]);
    }

    const size_t idx = (size_t)c * WKV_BH + ch;
    pa[idx] = a; pb[idx] = bs; pe[idx] = e;
}

// ---- K2: serial combine over chunks; P[c] <- incoming state S_c ----
__global__ __launch_bounds__(256)
void wkv_combine(float* __restrict__ pa, float* __restrict__ pb,
                 float* __restrict__ pe, const float* __restrict__ td,
                 int NC, int L)
{
    const int ch = blockIdx.x * 256 + threadIdx.x;   // 0..BH-1
    const float w  = -__expf(td[ch & (WKV_H - 1)]);
    const float Lw = w * (float)L;

    float a = 0.0f, bs = 0.0f, e = -INFINITY;
    for (int c = 0; c < NC; ++c) {
        const size_t idx = (size_t)c * WKV_BH + ch;
        float qa = pa[idx], qb = pb[idx], qe = pe[idx];
        pa[idx] = a; pb[idx] = bs; pe[idx] = e;      // incoming state for chunk c
        // S = decay(S, L*w) + Q   (chunk has real k's, so qe is finite)
        float ed = e + Lw;                            // -inf at c=0: fine
        float m  = fmaxf(ed, qe);
        float s1 = __expf(ed - m);                    // exp(-inf)=0 at c=0
        float s2 = __expf(qe - m);
        a  = fmaf(s1, a, s2 * qa);
        bs = fmaf(s1, bs, s2 * qb);
        e  = m;
    }
}

// ---- K3: outputs, starting from incoming state ----
__global__ __launch_bounds__(256)
void wkv_pass3(const float* __restrict__ k_, const float* __restrict__ v_,
               const float* __restrict__ td, const float* __restrict__ tf,
               const float* __restrict__ pa, const float* __restrict__ pb,
               const float* __restrict__ pe,
               float* __restrict__ out, int L)
{
    const int ch = blockIdx.x * 256 + threadIdx.x;
    const int c  = blockIdx.y;
    const int h  = ch & (WKV_H - 1);
    const int b  = ch >> 11;
    const float u = tf[h];
    const float w = -__expf(td[h]);

    const size_t base = (size_t)b * WKV_T * WKV_H + h + (size_t)c * L * WKV_H;
    const float* kp = k_ + base;
    const float* vp = v_ + base;
    float*       op = out + base;

    const size_t idx = (size_t)c * WKV_BH + ch;
    float a = pa[idx], bs = pb[idx], e = pe[idx];

    auto step = [&](float kt, float vt, float* outp) {
        float uk  = u + kt;
        float m   = fmaxf(e, uk);
        float wt  = __expf(uk - m);
        float sc  = __expf(e - m);
        float num = fmaf(wt, vt, a * sc);
        float den = fmaf(bs, sc, wt);
        *outp = num * __builtin_amdgcn_rcpf(den);
        wkv_update(a, bs, e, w, kt, vt);
    };

    float kA[WKV_U], vA[WKV_U], kB[WKV_U], vB[WKV_U];
    #pragma unroll
    for (int i = 0; i < WKV_U; ++i) {
        kA[i] = kp[(size_t)i * WKV_H];
        vA[i] = vp[(size_t)i * WKV_H];
    }
    for (int t0 = 0; t0 < L; t0 += 2 * WKV_U) {
        #pragma unroll
        for (int i = 0; i < WKV_U; ++i) {
            kB[i] = kp[(size_t)(t0 + WKV_U + i) * WKV_H];
            vB[i] = vp[(size_t)(t0 + WKV_U + i) * WKV_H];
        }
        #pragma unroll
        for (int i = 0; i < WKV_U; ++i)
            step(kA[i], vA[i], op + (size_t)(t0 + i) * WKV_H);
        if (t0 + 2 * WKV_U < L) {
            #pragma unroll
            for (int i = 0; i < WKV_U; ++i) {
                kA[i] = kp[(size_t)(t0 + 2 * WKV_U + i) * WKV_H];
                vA[i] = vp[(size_t)(t0 + 2 * WKV_U + i) * WKV_H];
            }
        }
        #pragma unroll
        for (int i = 0; i < WKV_U; ++i)
            step(kB[i], vB[i], op + (size_t)(t0 + WKV_U + i) * WKV_H);
    }
}

extern "C" void kernel_launch(void* const* d_in, const int* in_sizes, int n_in,
                              void* d_out, int out_size, void* d_ws, size_t ws_size,
                              hipStream_t stream) {
    const float* key   = (const float*)d_in[0];
    const float* value = (const float*)d_in[1];
    const float* td    = (const float*)d_in[2];
    const float* tf    = (const float*)d_in[3];
    float* out = (float*)d_out;

    // Pick the largest chunk count whose P-state fits in the workspace.
    int NC = 32;
    while (NC > 1 && (size_t)3 * sizeof(float) * WKV_BH * NC > ws_size) NC >>= 1;
    const int L = WKV_T / NC;                         // multiple of 16 (NC<=32)

    float* pa = (float*)d_ws;
    float* pb = pa + (size_t)WKV_BH * NC;
    float* pe = pb + (size_t)WKV_BH * NC;

    dim3 grid1(WKV_BH / 256, NC);
    wkv_pass1<<<grid1, 256, 0, stream>>>(key, value, td, pa, pb, pe, L);
    wkv_combine<<<WKV_BH / 256, 256, 0, stream>>>(pa, pb, pe, td, NC, L);
    wkv_pass3<<<grid1, 256, 0, stream>>>(key, value, td, tf, pa, pb, pe, out, L);
}

// Round 4
// 380.851 us; speedup vs baseline: 1.1357x; 1.0204x over previous
//
#include <hip/hip_runtime.h>
#include <math.h>

// RWKV WKV forward — chunked scan with LDS-DMA staged k/v tiles.
//
// R3 diagnosis: register ping-pong prefetch was sunk by the compiler
// (VGPR=32), leaving every wave latency-bound (VALUBusy 13%, same dur with
// L3-resident input). Fix: stage k/v through LDS with
// __builtin_amdgcn_global_load_lds (DMA cannot be sunk), double-buffered,
// counted s_waitcnt vmcnt(N) + raw s_barrier (never drain mid-loop).
//
//   K1: per (256-channel block, chunk) compute chunk-local state (a,b,e).
//   K2: per channel, serial combine over NC chunks -> incoming state S_c.
//   K3: same staging as K1, starts from S_c, emits outputs.

#define WKV_B 8
#define WKV_T 2048
#define WKV_H 2048
#define WKV_BH (WKV_B * WKV_H)
#define G_CH 256   // channels per block
#define SUB 8      // time-steps per LDS sub-tile (8 KB per array)

typedef const __attribute__((address_space(1))) void* gas_p;
typedef __attribute__((address_space(3))) void* las_p;

__device__ __forceinline__ void wkv_update(float& a, float& bs, float& e,
                                           float w, float kt, float vt) {
    float ew = e + w;
    float m2 = fmaxf(ew, kt);
    float s1 = __expf(ew - m2);
    float s2 = __expf(kt - m2);
    a  = fmaf(s1, a, s2 * vt);
    bs = fmaf(s1, bs, s2);
    e  = m2;
}

// Stage one SUB x G_CH sub-tile of k and v into LDS. Wave wid (0..3) DMAs
// rows {2*wid, 2*wid+1} of each array: one global_load_lds per row
// (64 lanes x 16 B = 1024 B = one row). 4 issues per wave.
__device__ __forceinline__ void stage_rows(const float* kbase, const float* vbase,
                                           float (*kl)[G_CH], float (*vl)[G_CH],
                                           int lane, int wid) {
    #pragma unroll
    for (int r = 0; r < 2; ++r) {
        const int s = 2 * wid + r;                       // wave-uniform
        const float* gk = kbase + (size_t)s * WKV_H + lane * 4;
        const float* gv = vbase + (size_t)s * WKV_H + lane * 4;
        __builtin_amdgcn_global_load_lds((gas_p)gk, (las_p)&kl[s][0], 16, 0, 0);
        __builtin_amdgcn_global_load_lds((gas_p)gv, (las_p)&vl[s][0], 16, 0, 0);
    }
}

// ---- K1: chunk-local state from identity ----
__global__ __launch_bounds__(256, 4)
void wkv_pass1(const float* __restrict__ k_, const float* __restrict__ v_,
               const float* __restrict__ td,
               float* __restrict__ pa, float* __restrict__ pb,
               float* __restrict__ pe, int L)
{
    __shared__ float kl[2][SUB][G_CH], vl[2][SUB][G_CH];
    const int tid  = threadIdx.x, lane = tid & 63, wid = tid >> 6;
    const int c    = blockIdx.y;
    const int ch   = blockIdx.x * G_CH + tid;            // 0..BH-1
    const int h    = ch & (WKV_H - 1);
    const int b    = ch >> 11;

    float w = -__expf(td[h]);
    asm volatile("" : "+v"(w));   // materialize before staging (vmcnt counting)

    const size_t base = (size_t)b * WKV_T * WKV_H + (size_t)c * L * WKV_H
                      + (size_t)(blockIdx.x * G_CH & (WKV_H - 1));
    const float* kp = k_ + base;
    const float* vp = v_ + base;

    float a = 0.0f, bs = 0.0f, e = -INFINITY;
    const int NSUB = L / SUB;

    stage_rows(kp, vp, kl[0], vl[0], lane, wid);
    if (NSUB > 1)
        stage_rows(kp + (size_t)SUB * WKV_H, vp + (size_t)SUB * WKV_H,
                   kl[1], vl[1], lane, wid);

    for (int s = 0; s < NSUB; ++s) {
        // wait for buf[s&1]'s DMA: outstanding allowed = stage(s+1)'s 4 issues
        if (s + 1 < NSUB) asm volatile("s_waitcnt vmcnt(4)" ::: "memory");
        else              asm volatile("s_waitcnt vmcnt(0)" ::: "memory");
        asm volatile("s_barrier" ::: "memory");
        const int cur = s & 1;
        #pragma unroll
        for (int i = 0; i < SUB; ++i)
            wkv_update(a, bs, e, w, kl[cur][i][tid], vl[cur][i][tid]);
        asm volatile("s_waitcnt lgkmcnt(0)" ::: "memory");
        asm volatile("s_barrier" ::: "memory");          // all waves done reading buf
        if (s + 2 < NSUB)
            stage_rows(kp + (size_t)(s + 2) * SUB * WKV_H,
                       vp + (size_t)(s + 2) * SUB * WKV_H,
                       kl[cur], vl[cur], lane, wid);
    }

    const size_t idx = (size_t)c * WKV_BH + ch;
    pa[idx] = a; pb[idx] = bs; pe[idx] = e;
}

// ---- K2: serial combine; P[c] <- incoming state S_c ----
__global__ __launch_bounds__(256)
void wkv_combine(float* __restrict__ pa, float* __restrict__ pb,
                 float* __restrict__ pe, const float* __restrict__ td,
                 int NC, int L)
{
    const int ch = blockIdx.x * 256 + threadIdx.x;
    const float w  = -__expf(td[ch & (WKV_H - 1)]);
    const float Lw = w * (float)L;

    float a = 0.0f, bs = 0.0f, e = -INFINITY;
    for (int c = 0; c < NC; ++c) {
        const size_t idx = (size_t)c * WKV_BH + ch;
        float qa = pa[idx], qb = pb[idx], qe = pe[idx];
        pa[idx] = a; pb[idx] = bs; pe[idx] = e;
        float ed = e + Lw;
        float m  = fmaxf(ed, qe);
        float s1 = __expf(ed - m);
        float s2 = __expf(qe - m);
        a  = fmaf(s1, a, s2 * qa);
        bs = fmaf(s1, bs, s2 * qb);
        e  = m;
    }
}

// ---- K3: outputs from incoming state, same LDS staging ----
__global__ __launch_bounds__(256, 4)
void wkv_pass3(const float* __restrict__ k_, const float* __restrict__ v_,
               const float* __restrict__ td, const float* __restrict__ tf,
               const float* __restrict__ pa, const float* __restrict__ pb,
               const float* __restrict__ pe,
               float* __restrict__ out, int L)
{
    __shared__ float kl[2][SUB][G_CH], vl[2][SUB][G_CH];
    const int tid  = threadIdx.x, lane = tid & 63, wid = tid >> 6;
    const int c    = blockIdx.y;
    const int ch   = blockIdx.x * G_CH + tid;
    const int h    = ch & (WKV_H - 1);
    const int b    = ch >> 11;

    const size_t idx = (size_t)c * WKV_BH + ch;
    float u = tf[h];
    float w = -__expf(td[h]);
    float a = pa[idx], bs = pb[idx], e = pe[idx];
    // materialize all pre-loop loads before the first DMA issue so the
    // in-loop vmcnt counts see only staging issues (+ out stores).
    asm volatile("" : "+v"(u), "+v"(w), "+v"(a), "+v"(bs), "+v"(e));

    const size_t base = (size_t)b * WKV_T * WKV_H + (size_t)c * L * WKV_H
                      + (size_t)(blockIdx.x * G_CH & (WKV_H - 1));
    const float* kp = k_ + base;
    const float* vp = v_ + base;
    float*       op = out + base + tid;

    const int NSUB = L / SUB;

    stage_rows(kp, vp, kl[0], vl[0], lane, wid);
    if (NSUB > 1)
        stage_rows(kp + (size_t)SUB * WKV_H, vp + (size_t)SUB * WKV_H,
                   kl[1], vl[1], lane, wid);

    for (int s = 0; s < NSUB; ++s) {
        // outstanding allowed: stage(s+1) [4] + this wave's 8 stores from
        // compute(s-1) issued before it. In-order vmcnt retirement.
        if (s == 0)               asm volatile("s_waitcnt vmcnt(4)"  ::: "memory");
        else if (s + 1 < NSUB)    asm volatile("s_waitcnt vmcnt(12)" ::: "memory");
        else                      asm volatile("s_waitcnt vmcnt(0)"  ::: "memory");
        asm volatile("s_barrier" ::: "memory");
        const int cur = s & 1;
        #pragma unroll
        for (int i = 0; i < SUB; ++i) {
            float kt = kl[cur][i][tid];
            float vt = vl[cur][i][tid];
            float uk  = u + kt;
            float m   = fmaxf(e, uk);
            float wt  = __expf(uk - m);
            float sc  = __expf(e - m);
            float num = fmaf(wt, vt, a * sc);
            float den = fmaf(bs, sc, wt);
            op[(size_t)(s * SUB + i) * WKV_H] = num * __builtin_amdgcn_rcpf(den);
            wkv_update(a, bs, e, w, kt, vt);
        }
        asm volatile("s_waitcnt lgkmcnt(0)" ::: "memory");
        asm volatile("s_barrier" ::: "memory");
        if (s + 2 < NSUB)
            stage_rows(kp + (size_t)(s + 2) * SUB * WKV_H,
                       vp + (size_t)(s + 2) * SUB * WKV_H,
                       kl[cur], vl[cur], lane, wid);
    }
}

extern "C" void kernel_launch(void* const* d_in, const int* in_sizes, int n_in,
                              void* d_out, int out_size, void* d_ws, size_t ws_size,
                              hipStream_t stream) {
    const float* key   = (const float*)d_in[0];
    const float* value = (const float*)d_in[1];
    const float* td    = (const float*)d_in[2];
    const float* tf    = (const float*)d_in[3];
    float* out = (float*)d_out;

    int NC = 32;                                   // L=64, NSUB=8
    while (NC > 1 && (size_t)3 * sizeof(float) * WKV_BH * NC > ws_size) NC >>= 1;
    const int L = WKV_T / NC;

    float* pa = (float*)d_ws;
    float* pb = pa + (size_t)WKV_BH * NC;
    float* pe = pb + (size_t)WKV_BH * NC;

    dim3 grid(WKV_BH / G_CH, NC);
    wkv_pass1<<<grid, 256, 0, stream>>>(key, value, td, pa, pb, pe, L);
    wkv_combine<<<WKV_BH / 256, 256, 0, stream>>>(pa, pb, pe, td, NC, L);
    wkv_pass3<<<grid, 256, 0, stream>>>(key, value, td, tf, pa, pb, pe, out, L);
}